// Round 3
// baseline (73.531 us; speedup 1.0000x reference)
//
#include <hip/hip_runtime.h>

#define N 4096
#define ROWS_PER_BLOCK 16
#define NBLOCKS (N / ROWS_PER_BLOCK)   // 256 blocks = 1 per CU
#define THREADS 512                    // 8 waves/block
#define R 4                            // rows per thread (LDS reuse factor)
#define CCHUNKS (THREADS / R)          // 128 j-chunks
#define JPT (N / CCHUNKS)              // 32 j-iterations per thread
#define NOTCH_THRESH 2.0f

// Full-matrix pairwise penalty; upper-triangle sum recovered as
// (full_sum - 4*N) * 0.5  (diagonal pair has d=0 -> penalty^2 = 4).
//
// Inner-loop algebra: relu(|xi-xj| - hxi - hxj) = max3(Li-Rj, Lj-Ri, 0)
// with L = x - hx, R = x + hx precomputed per element (tile = {Lx,Rx,Ly,Ry}).
// fmaxf(fmaxf(a,b),0) folds to a single v_max3_f32 -> 10 VALU/pair (was 12).
//
// Single kernel: last block (detected via memset-zeroed counter in d_ws)
// performs the deterministic final reduction and writes d_out — saves the
// second kernel node's launch gap in the captured graph.
__global__ __launch_bounds__(THREADS) void notch_fused(
    const float* __restrict__ pos,
    const float* __restrict__ sx,
    const float* __restrict__ sy,
    float* __restrict__ partial,
    unsigned int* __restrict__ counter,
    float* __restrict__ out)
{
    __shared__ float4 tile[N];                 // 64 KB: {Lx, Rx, Ly, Ry}
    __shared__ float red[THREADS / 64];
    __shared__ int is_last;

    const int tid = threadIdx.x;

    // Stage inputs into LDS with L/R precompute
    for (int j = tid; j < N; j += THREADS) {
        const float x  = pos[j];
        const float y  = pos[N + j];           // NUM_PHYS == N
        const float hx = 0.5f * sx[j];
        const float hy = 0.5f * sy[j];
        float4 t;
        t.x = x - hx;   // Lx
        t.y = x + hx;   // Rx
        t.z = y - hy;   // Ly
        t.w = y + hy;   // Ry
        tile[j] = t;
    }
    __syncthreads();

    // thread -> (row group g of R rows, j-chunk c)
    const int g  = tid & (R - 1);              // 0..3
    const int c  = tid >> 2;                   // 0..127; 4-lane broadcast groups
    const int i0 = blockIdx.x * ROWS_PER_BLOCK + g * R;

    const float4 me0 = tile[i0 + 0];
    const float4 me1 = tile[i0 + 1];
    const float4 me2 = tile[i0 + 2];
    const float4 me3 = tile[i0 + 3];

    float a0 = 0.0f, a1 = 0.0f, a2 = 0.0f, a3 = 0.0f;

#define PAIR(me, acc) {                                              \
        float dxp = fmaxf(fmaxf(me.x - t.y, t.x - me.y), 0.0f);      \
        float dyp = fmaxf(fmaxf(me.z - t.w, t.z - me.w), 0.0f);      \
        float p   = fmaxf(NOTCH_THRESH - (dxp + dyp), 0.0f);         \
        acc = fmaf(p, p, acc); }

    #pragma unroll 4
    for (int jj = 0; jj < JPT; ++jj) {
        const float4 t = tile[jj * CCHUNKS + c];
        PAIR(me0, a0)
        PAIR(me1, a1)
        PAIR(me2, a2)
        PAIR(me3, a3)
    }
#undef PAIR

    float acc = (a0 + a1) + (a2 + a3);

    // Deterministic in-block reduction: wave shuffle -> LDS -> block partial
    for (int off = 32; off > 0; off >>= 1)
        acc += __shfl_down(acc, off, 64);
    const int wave = tid >> 6;
    const int lane = tid & 63;
    if (lane == 0) red[wave] = acc;
    __syncthreads();

    if (tid == 0) {
        float s = 0.0f;
        #pragma unroll
        for (int w = 0; w < THREADS / 64; ++w) s += red[w];
        // Publish partial (agent-scope release), then signal completion.
        __hip_atomic_store(&partial[blockIdx.x], s, __ATOMIC_RELEASE,
                           __HIP_MEMORY_SCOPE_AGENT);
        const unsigned int old = __hip_atomic_fetch_add(
            counter, 1u, __ATOMIC_ACQ_REL, __HIP_MEMORY_SCOPE_AGENT);
        is_last = (old == NBLOCKS - 1);
    }
    __syncthreads();

    if (is_last) {
        // Last block: all 256 partials are published (acq_rel RMW chain).
        __shared__ float red2[NBLOCKS / 64];
        if (tid < NBLOCKS) {
            float v = __hip_atomic_load(&partial[tid], __ATOMIC_RELAXED,
                                        __HIP_MEMORY_SCOPE_AGENT);
            for (int off = 32; off > 0; off >>= 1)
                v += __shfl_down(v, off, 64);
            if ((tid & 63) == 0) red2[tid >> 6] = v;
        }
        __syncthreads();
        if (tid == 0) {
            float total = 0.0f;
            #pragma unroll
            for (int w = 0; w < NBLOCKS / 64; ++w) total += red2[w];
            out[0] = (total - 4.0f * (float)N) * 0.5f;
        }
    }
}

extern "C" void kernel_launch(void* const* d_in, const int* in_sizes, int n_in,
                              void* d_out, int out_size, void* d_ws, size_t ws_size,
                              hipStream_t stream) {
    const float* pos = (const float*)d_in[0];
    // d_in[1] = macro_mask (unused by the reference computation)
    const float* sx  = (const float*)d_in[2];
    const float* sy  = (const float*)d_in[3];
    float* out = (float*)d_out;

    unsigned int* counter = (unsigned int*)d_ws;          // 4 B at offset 0
    float* partial = (float*)((char*)d_ws + 256);         // 256 floats

    // Zero the completion counter (graph-capture-legal async memset node).
    hipMemsetAsync(counter, 0, sizeof(unsigned int), stream);

    notch_fused<<<NBLOCKS, THREADS, 0, stream>>>(pos, sx, sy, partial, counter, out);
}

// Round 4
// 65.253 us; speedup vs baseline: 1.1269x; 1.1269x over previous
//
#include <hip/hip_runtime.h>

#define N 4096
#define ROWS_PER_BLOCK 16
#define NBLOCKS (N / ROWS_PER_BLOCK)   // 256 blocks = 1 per CU
#define THREADS 512                    // 8 waves/block
#define R 4                            // rows per thread (LDS reuse factor)
#define CCHUNKS (THREADS / R)          // 128 j-chunks
#define JPT (N / CCHUNKS)              // 32 j-iterations per thread
#define NOTCH_THRESH 2.0f

// Full-matrix pairwise penalty; upper-triangle sum recovered as
// (full_sum - 4*N) * 0.5  (diagonal pair has d=0 -> penalty^2 = 4).
//
// Inner-loop algebra: relu(|xi-xj| - hxi - hxj) = max3(Li-Rj, Lj-Ri, 0)
// with L = x - hx, R = x + hx precomputed per element (tile = {Lx,Rx,Ly,Ry}).
// fmaxf(fmaxf(a,b),0) folds to a single v_max3_f32 -> 10 VALU/pair.
// (R3 post-mortem: single-kernel fusion via memset+counter was +8.4 us —
//  the 2-kernel structure below is the cheaper 2-node graph.)
__global__ __launch_bounds__(THREADS) void notch_main(
    const float* __restrict__ pos,
    const float* __restrict__ sx,
    const float* __restrict__ sy,
    float* __restrict__ partial)
{
    __shared__ float4 tile[N];                 // 64 KB: {Lx, Rx, Ly, Ry}
    __shared__ float red[THREADS / 64];

    const int tid = threadIdx.x;

    // Stage inputs into LDS with L/R precompute
    for (int j = tid; j < N; j += THREADS) {
        const float x  = pos[j];
        const float y  = pos[N + j];           // NUM_PHYS == N
        const float hx = 0.5f * sx[j];
        const float hy = 0.5f * sy[j];
        float4 t;
        t.x = x - hx;   // Lx
        t.y = x + hx;   // Rx
        t.z = y - hy;   // Ly
        t.w = y + hy;   // Ry
        tile[j] = t;
    }
    __syncthreads();

    // thread -> (row group g of R rows, j-chunk c)
    const int g  = tid & (R - 1);              // 0..3
    const int c  = tid >> 2;                   // 0..127; 4-lane broadcast groups
    const int i0 = blockIdx.x * ROWS_PER_BLOCK + g * R;

    const float4 me0 = tile[i0 + 0];
    const float4 me1 = tile[i0 + 1];
    const float4 me2 = tile[i0 + 2];
    const float4 me3 = tile[i0 + 3];

    float a0 = 0.0f, a1 = 0.0f, a2 = 0.0f, a3 = 0.0f;

#define PAIR(me, acc) {                                              \
        float dxp = fmaxf(fmaxf(me.x - t.y, t.x - me.y), 0.0f);      \
        float dyp = fmaxf(fmaxf(me.z - t.w, t.z - me.w), 0.0f);      \
        float p   = fmaxf(NOTCH_THRESH - (dxp + dyp), 0.0f);         \
        acc = fmaf(p, p, acc); }

    #pragma unroll 4
    for (int jj = 0; jj < JPT; ++jj) {
        const float4 t = tile[jj * CCHUNKS + c];
        PAIR(me0, a0)
        PAIR(me1, a1)
        PAIR(me2, a2)
        PAIR(me3, a3)
    }
#undef PAIR

    float acc = (a0 + a1) + (a2 + a3);

    // Deterministic reduction: wave shuffle -> LDS -> per-block partial
    for (int off = 32; off > 0; off >>= 1)
        acc += __shfl_down(acc, off, 64);
    const int wave = tid >> 6;
    const int lane = tid & 63;
    if (lane == 0) red[wave] = acc;
    __syncthreads();
    if (tid == 0) {
        float s = 0.0f;
        #pragma unroll
        for (int w = 0; w < THREADS / 64; ++w) s += red[w];
        partial[blockIdx.x] = s;
    }
}

// Single-wave final reduction: 64 lanes x 4 partials each, deterministic.
__global__ __launch_bounds__(64) void notch_final(
    const float* __restrict__ partial, float* __restrict__ out)
{
    const int tid = threadIdx.x;
    float v = (partial[tid] + partial[tid + 64])
            + (partial[tid + 128] + partial[tid + 192]);
    for (int off = 32; off > 0; off >>= 1)
        v += __shfl_down(v, off, 64);
    if (tid == 0)
        out[0] = (v - 4.0f * (float)N) * 0.5f;
}

extern "C" void kernel_launch(void* const* d_in, const int* in_sizes, int n_in,
                              void* d_out, int out_size, void* d_ws, size_t ws_size,
                              hipStream_t stream) {
    const float* pos = (const float*)d_in[0];
    // d_in[1] = macro_mask (unused by the reference computation)
    const float* sx  = (const float*)d_in[2];
    const float* sy  = (const float*)d_in[3];
    float* out     = (float*)d_out;
    float* partial = (float*)d_ws;   // 256 floats of scratch

    notch_main<<<NBLOCKS, THREADS, 0, stream>>>(pos, sx, sy, partial);
    notch_final<<<1, 64, 0, stream>>>(partial, out);
}